// Round 7
// baseline (736.532 us; speedup 1.0000x reference)
//
#include <hip/hip_runtime.h>

// ---------------- problem constants ----------------
constexpr int CB = 64;          // batch
constexpr int CHH = 14, CWW = 14;
constexpr int CN = 196;         // CHH*CWW
constexpr int CC = 1024;        // channels
constexpr int CROWS = CB * CN;  // 12544
constexpr int CKW = 8;          // rfft bins along W

// twiddles: cos/sin(2*pi*m/14), m=0..13
constexpr float C14[14] = {
  1.0f, 0.9009688679024191f, 0.6234898018587336f, 0.2225209339563144f,
  -0.2225209339563144f, -0.6234898018587336f, -0.9009688679024191f, -1.0f,
  -0.9009688679024191f, -0.6234898018587336f, -0.2225209339563144f,
  0.2225209339563144f, 0.6234898018587336f, 0.9009688679024191f };
constexpr float S14[14] = {
  0.0f, 0.4338837391175581f, 0.7818314824680298f, 0.9749279121818236f,
  0.9749279121818236f, 0.7818314824680298f, 0.4338837391175581f, 0.0f,
  -0.4338837391175581f, -0.7818314824680298f, -0.9749279121818236f,
  -0.9749279121818236f, -0.7818314824680298f, -0.4338837391175581f };

typedef __attribute__((ext_vector_type(8))) short bf16x8;
typedef __attribute__((ext_vector_type(4))) float f32x4;

__device__ __forceinline__ unsigned short f2bf(float f) {
  unsigned u = __builtin_bit_cast(unsigned, f);
  u += 0x7FFFu + ((u >> 16) & 1u);   // RNE
  return (unsigned short)(u >> 16);
}
__device__ __forceinline__ float bf2f(unsigned short h) {
  return __builtin_bit_cast(float, (unsigned)h << 16);
}

__device__ __forceinline__ void gload_lds16(const void* g, void* l) {
  __builtin_amdgcn_global_load_lds(
      (const __attribute__((address_space(1))) void*)g,
      (__attribute__((address_space(3))) void*)l, 16, 0, 0);
}

#define WAITV(N)  asm volatile("s_waitcnt vmcnt(" #N ")" ::: "memory")
#define SBAR()    asm volatile("s_barrier" ::: "memory")

// ---------------- LayerNorm over C=1024 (one block per row) ----------------
template<int OUTBF>
__global__ __launch_bounds__(256)
void ln_kernel(const float* __restrict__ in, const float* __restrict__ gam,
               const float* __restrict__ bet, float* __restrict__ outf,
               unsigned short* __restrict__ outb)
{
  const int row = blockIdx.x;
  const int t = threadIdx.x;
  const float4 v = *(const float4*)(in + (size_t)row * CC + t * 4);
  float s  = v.x + v.y + v.z + v.w;
  float s2 = v.x*v.x + v.y*v.y + v.z*v.z + v.w*v.w;
  #pragma unroll
  for (int o = 32; o > 0; o >>= 1) { s += __shfl_down(s, o); s2 += __shfl_down(s2, o); }
  __shared__ float red[8];
  const int wid = t >> 6, lane = t & 63;
  if (lane == 0) { red[wid] = s; red[4 + wid] = s2; }
  __syncthreads();
  s  = red[0] + red[1] + red[2] + red[3];
  s2 = red[4] + red[5] + red[6] + red[7];
  const float mean = s * (1.0f / CC);
  const float var  = s2 * (1.0f / CC) - mean * mean;
  const float r = rsqrtf(var + 1e-5f);
  const float4 g4 = *(const float4*)(gam + t * 4);
  const float4 b4 = *(const float4*)(bet + t * 4);
  const float o0 = (v.x - mean) * r * g4.x + b4.x;
  const float o1 = (v.y - mean) * r * g4.y + b4.y;
  const float o2 = (v.z - mean) * r * g4.z + b4.z;
  const float o3 = (v.w - mean) * r * g4.w + b4.w;
  if (OUTBF) {
    ushort4 p; p.x = f2bf(o0); p.y = f2bf(o1); p.z = f2bf(o2); p.w = f2bf(o3);
    *(ushort4*)(outb + (size_t)row * CC + t * 4) = p;
  } else {
    *(float4*)(outf + (size_t)row * CC + t * 4) = make_float4(o0, o1, o2, o3);
  }
}

// ---------------- rfft along W: [B,H,W,C] real -> [B,H,8,C] complex ----------------
__global__ __launch_bounds__(256)
void fft_w_fwd(const float* __restrict__ y, float* __restrict__ Ar, float* __restrict__ Ai)
{
  const int t = threadIdx.x;
  const int bid = blockIdx.x;      // ((b*14)+h)*4 + cc
  const int cc = bid & 3;
  const int tmp = bid >> 2;
  const int h = tmp % 14;
  const int b = tmp / 14;
  const int c = cc * 256 + t;
  const size_t base = ((size_t)b * CN + (size_t)h * CWW) * CC + c;
  float v[14];
  #pragma unroll
  for (int w = 0; w < 14; w++) v[w] = y[base + (size_t)w * CC];
  const size_t obase = (((size_t)b * CHH + h) * CKW) * CC + c;
  #pragma unroll
  for (int kw = 0; kw < 8; kw++) {
    float sr = 0.f, si = 0.f;
    #pragma unroll
    for (int w = 0; w < 14; w++) {
      const int m = (w * kw) % 14;
      sr += v[w] * C14[m];
      si -= v[w] * S14[m];
    }
    Ar[obase + (size_t)kw * CC] = sr;
    Ai[obase + (size_t)kw * CC] = si;
  }
}

// ---------------- fft along H + complex filter + ifft along H ----------------
__global__ __launch_bounds__(256)
void fft_h_filt(const float* __restrict__ Ar, const float* __restrict__ Ai,
                const float* __restrict__ cw, float* __restrict__ Br, float* __restrict__ Bi)
{
  const int t = threadIdx.x;
  const int bid = blockIdx.x;      // ((b*8)+kw)*4 + cc
  const int cc = bid & 3;
  const int tmp = bid >> 2;
  const int kw = tmp & 7;
  const int b = tmp >> 3;
  const int c = cc * 256 + t;
  const size_t base = (((size_t)b * CHH) * CKW + kw) * CC + c;   // h stride = CKW*CC
  float ar[14], ai[14];
  #pragma unroll
  for (int h = 0; h < 14; h++) {
    ar[h] = Ar[base + (size_t)h * (CKW * CC)];
    ai[h] = Ai[base + (size_t)h * (CKW * CC)];
  }
  float fr[14], fi[14];
  #pragma unroll
  for (int kh = 0; kh < 14; kh++) {
    float yr = 0.f, yi = 0.f;
    #pragma unroll
    for (int h = 0; h < 14; h++) {
      const int m = (h * kh) % 14;
      yr += ar[h] * C14[m] + ai[h] * S14[m];
      yi += ai[h] * C14[m] - ar[h] * S14[m];
    }
    const size_t widx = (((size_t)kh * CKW + kw) * CC + c) * 2;
    const float wr = cw[widx], wi = cw[widx + 1];
    fr[kh] = yr * wr - yi * wi;
    fi[kh] = yr * wi + yi * wr;
  }
  #pragma unroll
  for (int h = 0; h < 14; h++) {
    float sr = 0.f, si = 0.f;
    #pragma unroll
    for (int kh = 0; kh < 14; kh++) {
      const int m = (h * kh) % 14;
      sr += fr[kh] * C14[m] - fi[kh] * S14[m];
      si += fr[kh] * S14[m] + fi[kh] * C14[m];
    }
    Br[base + (size_t)h * (CKW * CC)] = sr;
    Bi[base + (size_t)h * (CKW * CC)] = si;
  }
}

// ---------------- irfft along W (c2r: imag of DC/Nyquist ignored) ----------------
__global__ __launch_bounds__(256)
void fft_w_inv(const float* __restrict__ Br, const float* __restrict__ Bi, float* __restrict__ y2)
{
  const int t = threadIdx.x;
  const int bid = blockIdx.x;
  const int cc = bid & 3;
  const int tmp = bid >> 2;
  const int h = tmp % 14;
  const int b = tmp / 14;
  const int c = cc * 256 + t;
  const size_t ibase = (((size_t)b * CHH + h) * CKW) * CC + c;
  float br[8], bi[8];
  #pragma unroll
  for (int k = 0; k < 8; k++) {
    br[k] = Br[ibase + (size_t)k * CC];
    bi[k] = Bi[ibase + (size_t)k * CC];
  }
  const size_t obase = ((size_t)b * CN + (size_t)h * CWW) * CC + c;
  #pragma unroll
  for (int w = 0; w < 14; w++) {
    float s = br[0] + ((w & 1) ? -br[7] : br[7]);
    #pragma unroll
    for (int k = 1; k < 7; k++) {
      const int m = (w * k) % 14;
      s += 2.0f * (br[k] * C14[m] - bi[k] * S14[m]);
    }
    y2[obase + (size_t)w * CC] = s * (1.0f / 196.0f);   // ortho fwd*inv = 1/196
  }
}

// ---------------- transpose fp32 [R,Cc] -> bf16 [Cc,R] ----------------
__global__ __launch_bounds__(256)
void transpose_f32_bf16(const float* __restrict__ in, unsigned short* __restrict__ out,
                        int R, int Ccols)
{
  __shared__ float tile[32][33];
  const int tx = threadIdx.x & 31;
  const int ty = threadIdx.x >> 5;     // 0..7
  const int cb = blockIdx.x * 32;
  const int rb = blockIdx.y * 32;
  #pragma unroll
  for (int i = 0; i < 32; i += 8)
    tile[ty + i][tx] = in[(size_t)(rb + ty + i) * Ccols + cb + tx];
  __syncthreads();
  #pragma unroll
  for (int i = 0; i < 32; i += 8)
    out[(size_t)(cb + ty + i) * R + rb + tx] = f2bf(tile[tx][ty + i]);
}

// ---------------- 128x128 bf16 GEMM: A via LDS dbuf, B global->regs ----------------
// C[M,N] = A[M,K] * BT[N,K]^T, +bias, optional exact GELU, bf16 out.
// 256 thr = 4 waves (2M x 2N, 64x64 each); BK=64.
// LDS: only A, 2 x [128][64] bf16 = 32 KB -> 2+ blocks/CU co-resident; barriers
// are per-block so co-resident blocks de-phase (cross-block TLP overlaps one
// block's LDS/stage phase with the other's MFMA burst) - the m97 mechanism.
// B is loaded straight global->VGPR (dbuf'd bfX/bfY), killing B's LDS traffic;
// wm=0/1 waves issue identical B loads -> L1/L2 hits.
// Per-wave VMEM ledger: 12/tile (4 A-glds then 8 B-loads), issued 1 tile ahead.
//   entry: vmcnt(8)  -> A(T) LDS writes landed (own wave) ; s_barrier -> all
//   after issuing T+1's 12: vmcnt(12) -> B(T) regs ready, T+1 stays in flight
//   last tile: vmcnt(0).
// A LDS swizzle: read byte col ^= (row&7)<<4; staged via inverse-swizzled
// global source col with linear glds dest (both-sides-or-neither, rule #21).
#define TILE128(TT, CUR, NXT, BCUR, BNXT) do {                                \
  WAITV(8);                                                                   \
  SBAR();                                                                     \
  if ((TT) + 1 < NT) {                                                        \
    const int _gc = ((TT) + 1) * 64 + cl;                                     \
    gload_lds16(A + (size_t)(brow + ar0     ) * K + _gc, (NXT) + dst0);       \
    gload_lds16(A + (size_t)(brow + ar0 + 32) * K + _gc, (NXT) + dst0 + 4096);\
    gload_lds16(A + (size_t)(brow + ar0 + 64) * K + _gc, (NXT) + dst0 + 8192);\
    gload_lds16(A + (size_t)(brow + ar0 + 96) * K + _gc, (NXT) + dst0 + 12288);\
    _Pragma("unroll")                                                         \
    for (int nf = 0; nf < 4; ++nf) {                                          \
      const size_t _b = (size_t)(bcol + wn * 64 + nf * 16 + lrow) * K         \
                        + ((TT) + 1) * 64 + qe;                               \
      BNXT[nf][0] = *(const bf16x8*)(BT + _b);                                \
      BNXT[nf][1] = *(const bf16x8*)(BT + _b + 32);                           \
    }                                                                         \
  }                                                                           \
  _Pragma("unroll")                                                           \
  for (int mf = 0; mf < 4; ++mf) {                                            \
    const int row = wm * 64 + mf * 16 + lrow;                                 \
    const int sw = (row & 7) << 4;                                            \
    af[mf][0] = *(const bf16x8*)((CUR) + row * 128 + ((0  | dq) ^ sw));       \
    af[mf][1] = *(const bf16x8*)((CUR) + row * 128 + ((64 | dq) ^ sw));       \
  }                                                                           \
  if ((TT) + 1 < NT) { WAITV(12); } else { WAITV(0); }                        \
  __builtin_amdgcn_s_setprio(1);                                              \
  _Pragma("unroll")                                                           \
  for (int ks = 0; ks < 2; ++ks)                                              \
    _Pragma("unroll")                                                         \
    for (int mf = 0; mf < 4; ++mf)                                            \
      _Pragma("unroll")                                                       \
      for (int nf = 0; nf < 4; ++nf)                                          \
        acc[mf][nf] = __builtin_amdgcn_mfma_f32_16x16x32_bf16(                \
            af[mf][ks], BCUR[nf][ks], acc[mf][nf], 0, 0, 0);                  \
  __builtin_amdgcn_s_setprio(0);                                              \
} while (0)

template<int DO_GELU>
__global__ __launch_bounds__(256, 2)
void gemm128(const unsigned short* __restrict__ A, const unsigned short* __restrict__ BT,
             const float* __restrict__ bias, unsigned short* __restrict__ C,
             int M, int N, int K)
{
  __shared__ __align__(16) short As0[128 * 64];
  __shared__ __align__(16) short As1[128 * 64];
  char* a0 = (char*)As0; char* a1 = (char*)As1;

  const int t = threadIdx.x;
  const int wid = t >> 6, lane = t & 63;
  const int wm = wid >> 1, wn = wid & 1;
  const int lrow = lane & 15, qk = lane >> 4;
  const int dq = qk << 4;          // byte offset of k-quarter
  const int qe = qk << 3;          // element offset of k-quarter

  // T1: bijective XCD swizzle (m204; nwg % 8 == 0 here) + GROUP=8 along N
  const int nbx = N >> 7, nby = M >> 7;
  const int nwg = nbx * nby;
  const int orig = blockIdx.x;
  const int q8 = nwg >> 3, xcd = orig & 7, lid = orig >> 3;
  const int wg = xcd * q8 + lid;
  const int gw = 8 * nby;
  const int gid = wg / gw, rem = wg % gw;
  const int bx = gid * 8 + (rem & 7);
  const int by = rem >> 3;
  const int brow = by << 7, bcol = bx << 7;
  const int NT = K >> 6;

  // staging per-thread constants (A: 128 rows x 64 elems, 4 glds/thread/tile)
  const int ar0 = t >> 3;                      // 0..31
  const int cl = ((t ^ (t >> 3)) & 7) << 3;    // inverse-swizzled element col
  const int dst0 = t * 16;                     // linear LDS dest byte

  f32x4 acc[4][4] = {};
  bf16x8 af[4][2], bfX[4][2], bfY[4][2];

  // prologue: A(0) glds + B(0) global->bfX  (12 VMEM outstanding = steady state)
  {
    gload_lds16(A + (size_t)(brow + ar0     ) * K + cl, a0 + dst0);
    gload_lds16(A + (size_t)(brow + ar0 + 32) * K + cl, a0 + dst0 + 4096);
    gload_lds16(A + (size_t)(brow + ar0 + 64) * K + cl, a0 + dst0 + 8192);
    gload_lds16(A + (size_t)(brow + ar0 + 96) * K + cl, a0 + dst0 + 12288);
    #pragma unroll
    for (int nf = 0; nf < 4; ++nf) {
      const size_t _b = (size_t)(bcol + wn * 64 + nf * 16 + lrow) * K + qe;
      bfX[nf][0] = *(const bf16x8*)(BT + _b);
      bfX[nf][1] = *(const bf16x8*)(BT + _b + 32);
    }
  }

  for (int T = 0; T < NT; T += 2) {
    TILE128(T,     a0, a1, bfX, bfY);
    TILE128(T + 1, a1, a0, bfY, bfX);
  }

  // epilogue: bias (+GELU) + bf16 store
  #pragma unroll
  for (int mf = 0; mf < 4; ++mf) {
    #pragma unroll
    for (int nf = 0; nf < 4; ++nf) {
      const int ccol = bcol + wn * 64 + nf * 16 + lrow;
      const float bb = bias[ccol];
      #pragma unroll
      for (int j = 0; j < 4; ++j) {
        const int r = brow + wm * 64 + mf * 16 + qk * 4 + j;
        float v = acc[mf][nf][j] + bb;
        if (DO_GELU) v = 0.5f * v * (1.0f + erff(v * 0.70710678118654752f));
        C[(size_t)r * N + ccol] = f2bf(v);
      }
    }
  }
}

// ---------------- FEM: 3 blockwise instance-norm gates fused + residual ----------------
__device__ __forceinline__ void fem_block(unsigned short* col, int t,
                                          int h0, int nh, int w0, int nw)
{
  float s = 0.f, s2 = 0.f;
  for (int ih = 0; ih < nh; ih++)
    for (int iw = 0; iw < nw; iw++) {
      const float v = bf2f(col[((h0 + ih) * 14 + w0 + iw) * 128 + t]);
      s += v; s2 += v * v;
    }
  const float inv = 1.0f / (float)(nh * nw);
  const float m = s * inv;
  const float var = s2 * inv - m * m;
  const float r = rsqrtf(var + 1e-5f);
  for (int ih = 0; ih < nh; ih++)
    for (int iw = 0; iw < nw; iw++) {
      const int idx = ((h0 + ih) * 14 + w0 + iw) * 128 + t;
      const float v = bf2f(col[idx]);
      const float a = 1.0f / (1.0f + __expf(-(v - m) * r));
      col[idx] = f2bf(0.5f * v * (1.0f + a));
    }
}

__global__ __launch_bounds__(128)
void fem_kernel(const unsigned short* __restrict__ z, const float* __restrict__ x,
                float* __restrict__ out)
{
  __shared__ unsigned short buf[CN * 128];   // 50,176 B; thread-private columns
  const int t = threadIdx.x;
  const int b = blockIdx.x >> 3;
  const int cc = blockIdx.x & 7;
  const int c = cc * 128 + t;
  const size_t base = (size_t)b * CN * CC + c;
  #pragma unroll 4
  for (int n = 0; n < CN; n++) buf[n * 128 + t] = z[base + (size_t)n * CC];
  // s = 3: 5x5 blocks, row/col starts {0,3,6,9,12}, lens {3,3,3,3,2}
  const int st3[5] = {0, 3, 6, 9, 12};
  const int ln3[5] = {3, 3, 3, 3, 2};
  for (int i = 0; i < 5; i++)
    for (int j = 0; j < 5; j++)
      fem_block(buf, t, st3[i], ln3[i], st3[j], ln3[j]);
  // s = 7: 2x2 blocks of 7x7
  for (int i = 0; i < 2; i++)
    for (int j = 0; j < 2; j++)
      fem_block(buf, t, i * 7, 7, j * 7, 7);
  // s = 14: whole field
  fem_block(buf, t, 0, 14, 0, 14);
  #pragma unroll 4
  for (int n = 0; n < CN; n++)
    out[base + (size_t)n * CC] = x[base + (size_t)n * CC] + bf2f(buf[n * 128 + t]);
}

// ---------------- launch ----------------
extern "C" void kernel_launch(void* const* d_in, const int* in_sizes, int n_in,
                              void* d_out, int out_size, void* d_ws, size_t ws_size,
                              hipStream_t stream) {
  const float* x     = (const float*)d_in[0];
  const float* ln1_g = (const float*)d_in[1];
  const float* ln1_b = (const float*)d_in[2];
  const float* cw    = (const float*)d_in[3];
  const float* ln2_g = (const float*)d_in[4];
  const float* ln2_b = (const float*)d_in[5];
  const float* fc1_w = (const float*)d_in[6];
  const float* fc1_b = (const float*)d_in[7];
  const float* fc2_w = (const float*)d_in[8];
  const float* fc2_b = (const float*)d_in[9];
  float* out = (float*)d_out;
  char* ws = (char*)d_ws;

  // arena (total 161.5 MB); d_out doubles as fp32 scratch for y1/y2
  const size_t SZ_A = (size_t)CB * CHH * CKW * CC * 4;       // 29,360,128 B
  float* Ar = (float*)(ws);
  float* Ai = (float*)(ws + SZ_A);
  float* Br = (float*)(ws + 2 * SZ_A);
  float* Bi = (float*)(ws + 3 * SZ_A);
  unsigned short* A1   = (unsigned short*)(ws);                        // after FFT done
  unsigned short* W1T  = (unsigned short*)(ws + SZ_A);                 // [4096,1024] bf16
  unsigned short* W2T  = (unsigned short*)(ws + SZ_A + (size_t)4096 * 1024 * 2); // [1024,4096]
  unsigned short* Hmid = (unsigned short*)(ws + 2 * SZ_A);             // [12544,4096] bf16
  unsigned short* Z    = (unsigned short*)(ws);                        // [12544,1024] bf16

  // 1. LN1: x -> y1 (in d_out)
  ln_kernel<0><<<CROWS, 256, 0, stream>>>(x, ln1_g, ln1_b, out, nullptr);
  // 2. rfft along W
  fft_w_fwd<<<CB * CHH * 4, 256, 0, stream>>>(out, Ar, Ai);
  // 3. fft along H + filter + ifft along H
  fft_h_filt<<<CB * CKW * 4, 256, 0, stream>>>(Ar, Ai, cw, Br, Bi);
  // 4. irfft along W -> y2 (in d_out)
  fft_w_inv<<<CB * CHH * 4, 256, 0, stream>>>(Br, Bi, out);
  // 5. LN2 -> bf16 A1
  ln_kernel<1><<<CROWS, 256, 0, stream>>>(out, ln2_g, ln2_b, nullptr, A1);
  // 6. weight prep (FFT intermediates dead)
  transpose_f32_bf16<<<dim3(4096 / 32, 1024 / 32), 256, 0, stream>>>(fc1_w, W1T, 1024, 4096);
  transpose_f32_bf16<<<dim3(1024 / 32, 4096 / 32), 256, 0, stream>>>(fc2_w, W2T, 4096, 1024);
  // 7. GEMM1 + bias + exact GELU -> Hmid bf16 (grid 32x98 = 3136)
  gemm128<1><<<dim3(3136), 256, 0, stream>>>(A1, W1T, fc1_b, Hmid, CROWS, 4096, 1024);
  // 8. GEMM2 + bias -> Z bf16 (grid 8x98 = 784)
  gemm128<0><<<dim3(784), 256, 0, stream>>>(Hmid, W2T, fc2_b, Z, CROWS, 1024, 4096);
  // 9. FEM x3 fused + residual -> out
  fem_kernel<<<CB * 8, 128, 0, stream>>>(Z, x, out);
}

// Round 8
// 504.672 us; speedup vs baseline: 1.4594x; 1.4594x over previous
//
#include <hip/hip_runtime.h>

// ---------------- problem constants ----------------
constexpr int CB = 64;          // batch
constexpr int CHH = 14, CWW = 14;
constexpr int CN = 196;         // CHH*CWW
constexpr int CC = 1024;        // channels
constexpr int CROWS = CB * CN;  // 12544
constexpr int CKW = 8;          // rfft bins along W

// twiddles: cos/sin(2*pi*m/14), m=0..13
constexpr float C14[14] = {
  1.0f, 0.9009688679024191f, 0.6234898018587336f, 0.2225209339563144f,
  -0.2225209339563144f, -0.6234898018587336f, -0.9009688679024191f, -1.0f,
  -0.9009688679024191f, -0.6234898018587336f, -0.2225209339563144f,
  0.2225209339563144f, 0.6234898018587336f, 0.9009688679024191f };
constexpr float S14[14] = {
  0.0f, 0.4338837391175581f, 0.7818314824680298f, 0.9749279121818236f,
  0.9749279121818236f, 0.7818314824680298f, 0.4338837391175581f, 0.0f,
  -0.4338837391175581f, -0.7818314824680298f, -0.9749279121818236f,
  -0.9749279121818236f, -0.7818314824680298f, -0.4338837391175581f };

typedef __attribute__((ext_vector_type(8))) short bf16x8;
typedef __attribute__((ext_vector_type(4))) float f32x4;

__device__ __forceinline__ unsigned short f2bf(float f) {
  unsigned u = __builtin_bit_cast(unsigned, f);
  u += 0x7FFFu + ((u >> 16) & 1u);   // RNE
  return (unsigned short)(u >> 16);
}
__device__ __forceinline__ float bf2f(unsigned short h) {
  return __builtin_bit_cast(float, (unsigned)h << 16);
}

__device__ __forceinline__ void gload_lds16(const void* g, void* l) {
  __builtin_amdgcn_global_load_lds(
      (const __attribute__((address_space(1))) void*)g,
      (__attribute__((address_space(3))) void*)l, 16, 0, 0);
}

#define WAITV(N)  asm volatile("s_waitcnt vmcnt(" #N ")" ::: "memory")

// ---------------- LayerNorm over C=1024 (one block per row) ----------------
template<int OUTBF>
__global__ __launch_bounds__(256)
void ln_kernel(const float* __restrict__ in, const float* __restrict__ gam,
               const float* __restrict__ bet, float* __restrict__ outf,
               unsigned short* __restrict__ outb)
{
  const int row = blockIdx.x;
  const int t = threadIdx.x;
  const float4 v = *(const float4*)(in + (size_t)row * CC + t * 4);
  float s  = v.x + v.y + v.z + v.w;
  float s2 = v.x*v.x + v.y*v.y + v.z*v.z + v.w*v.w;
  #pragma unroll
  for (int o = 32; o > 0; o >>= 1) { s += __shfl_down(s, o); s2 += __shfl_down(s2, o); }
  __shared__ float red[8];
  const int wid = t >> 6, lane = t & 63;
  if (lane == 0) { red[wid] = s; red[4 + wid] = s2; }
  __syncthreads();
  s  = red[0] + red[1] + red[2] + red[3];
  s2 = red[4] + red[5] + red[6] + red[7];
  const float mean = s * (1.0f / CC);
  const float var  = s2 * (1.0f / CC) - mean * mean;
  const float r = rsqrtf(var + 1e-5f);
  const float4 g4 = *(const float4*)(gam + t * 4);
  const float4 b4 = *(const float4*)(bet + t * 4);
  const float o0 = (v.x - mean) * r * g4.x + b4.x;
  const float o1 = (v.y - mean) * r * g4.y + b4.y;
  const float o2 = (v.z - mean) * r * g4.z + b4.z;
  const float o3 = (v.w - mean) * r * g4.w + b4.w;
  if (OUTBF) {
    ushort4 p; p.x = f2bf(o0); p.y = f2bf(o1); p.z = f2bf(o2); p.w = f2bf(o3);
    *(ushort4*)(outb + (size_t)row * CC + t * 4) = p;
  } else {
    *(float4*)(outf + (size_t)row * CC + t * 4) = make_float4(o0, o1, o2, o3);
  }
}

// ---------------- rfft along W: [B,H,W,C] real -> [B,H,8,C] complex ----------------
__global__ __launch_bounds__(256)
void fft_w_fwd(const float* __restrict__ y, float* __restrict__ Ar, float* __restrict__ Ai)
{
  const int t = threadIdx.x;
  const int bid = blockIdx.x;      // ((b*14)+h)*4 + cc
  const int cc = bid & 3;
  const int tmp = bid >> 2;
  const int h = tmp % 14;
  const int b = tmp / 14;
  const int c = cc * 256 + t;
  const size_t base = ((size_t)b * CN + (size_t)h * CWW) * CC + c;
  float v[14];
  #pragma unroll
  for (int w = 0; w < 14; w++) v[w] = y[base + (size_t)w * CC];
  const size_t obase = (((size_t)b * CHH + h) * CKW) * CC + c;
  #pragma unroll
  for (int kw = 0; kw < 8; kw++) {
    float sr = 0.f, si = 0.f;
    #pragma unroll
    for (int w = 0; w < 14; w++) {
      const int m = (w * kw) % 14;
      sr += v[w] * C14[m];
      si -= v[w] * S14[m];
    }
    Ar[obase + (size_t)kw * CC] = sr;
    Ai[obase + (size_t)kw * CC] = si;
  }
}

// ---------------- fft along H + complex filter + ifft along H ----------------
__global__ __launch_bounds__(256)
void fft_h_filt(const float* __restrict__ Ar, const float* __restrict__ Ai,
                const float* __restrict__ cw, float* __restrict__ Br, float* __restrict__ Bi)
{
  const int t = threadIdx.x;
  const int bid = blockIdx.x;      // ((b*8)+kw)*4 + cc
  const int cc = bid & 3;
  const int tmp = bid >> 2;
  const int kw = tmp & 7;
  const int b = tmp >> 3;
  const int c = cc * 256 + t;
  const size_t base = (((size_t)b * CHH) * CKW + kw) * CC + c;   // h stride = CKW*CC
  float ar[14], ai[14];
  #pragma unroll
  for (int h = 0; h < 14; h++) {
    ar[h] = Ar[base + (size_t)h * (CKW * CC)];
    ai[h] = Ai[base + (size_t)h * (CKW * CC)];
  }
  float fr[14], fi[14];
  #pragma unroll
  for (int kh = 0; kh < 14; kh++) {
    float yr = 0.f, yi = 0.f;
    #pragma unroll
    for (int h = 0; h < 14; h++) {
      const int m = (h * kh) % 14;
      yr += ar[h] * C14[m] + ai[h] * S14[m];
      yi += ai[h] * C14[m] - ar[h] * S14[m];
    }
    const size_t widx = (((size_t)kh * CKW + kw) * CC + c) * 2;
    const float wr = cw[widx], wi = cw[widx + 1];
    fr[kh] = yr * wr - yi * wi;
    fi[kh] = yr * wi + yi * wr;
  }
  #pragma unroll
  for (int h = 0; h < 14; h++) {
    float sr = 0.f, si = 0.f;
    #pragma unroll
    for (int kh = 0; kh < 14; kh++) {
      const int m = (h * kh) % 14;
      sr += fr[kh] * C14[m] - fi[kh] * S14[m];
      si += fr[kh] * S14[m] + fi[kh] * C14[m];
    }
    Br[base + (size_t)h * (CKW * CC)] = sr;
    Bi[base + (size_t)h * (CKW * CC)] = si;
  }
}

// ---------------- irfft along W (c2r: imag of DC/Nyquist ignored) ----------------
__global__ __launch_bounds__(256)
void fft_w_inv(const float* __restrict__ Br, const float* __restrict__ Bi, float* __restrict__ y2)
{
  const int t = threadIdx.x;
  const int bid = blockIdx.x;
  const int cc = bid & 3;
  const int tmp = bid >> 2;
  const int h = tmp % 14;
  const int b = tmp / 14;
  const int c = cc * 256 + t;
  const size_t ibase = (((size_t)b * CHH + h) * CKW) * CC + c;
  float br[8], bi[8];
  #pragma unroll
  for (int k = 0; k < 8; k++) {
    br[k] = Br[ibase + (size_t)k * CC];
    bi[k] = Bi[ibase + (size_t)k * CC];
  }
  const size_t obase = ((size_t)b * CN + (size_t)h * CWW) * CC + c;
  #pragma unroll
  for (int w = 0; w < 14; w++) {
    float s = br[0] + ((w & 1) ? -br[7] : br[7]);
    #pragma unroll
    for (int k = 1; k < 7; k++) {
      const int m = (w * k) % 14;
      s += 2.0f * (br[k] * C14[m] - bi[k] * S14[m]);
    }
    y2[obase + (size_t)w * CC] = s * (1.0f / 196.0f);   // ortho fwd*inv = 1/196
  }
}

// ---------------- transpose fp32 [R,Cc] -> bf16 [Cc,R] ----------------
__global__ __launch_bounds__(256)
void transpose_f32_bf16(const float* __restrict__ in, unsigned short* __restrict__ out,
                        int R, int Ccols)
{
  __shared__ float tile[32][33];
  const int tx = threadIdx.x & 31;
  const int ty = threadIdx.x >> 5;     // 0..7
  const int cb = blockIdx.x * 32;
  const int rb = blockIdx.y * 32;
  #pragma unroll
  for (int i = 0; i < 32; i += 8)
    tile[ty + i][tx] = in[(size_t)(rb + ty + i) * Ccols + cb + tx];
  __syncthreads();
  #pragma unroll
  for (int i = 0; i < 32; i += 8)
    out[(size_t)(cb + ty + i) * R + rb + tx] = f2bf(tile[tx][ty + i]);
}

// ---------------- 128x128 bf16 GEMM, m97-faithful: single-buffer LDS, 4 blocks/CU ----
// C[M,N] = A[M,K] * BT[N,K]^T, +bias, optional exact GELU, bf16 out.
// 256 thr = 4 waves (2x2, 64x64/wave); BK=32; LDS = A 8KB + B 8KB single-buffered
// -> 16KB/block, <=128 VGPR (launch_bounds 256,4) -> 4 blocks/CU co-resident.
// The per-step vmcnt(0)+syncthreads drain is hidden by sibling blocks' MFMA
// (the m97/m102 mechanism: 874 TF needs 3-4 co-resident blocks).
// LDS layout: row-pairs packed into 128B rows: A[r][e] at byte
//   (r>>1)*128 + ((((r&1)<<6) | e*2) ^ (((r>>1)&7)<<4))
// -> frag reads are 2-way/bank (free); staging is linear-dest glds with the
// inverse-swizzled global source (both-sides-or-neither, rule #21).
// Block order: groups of 8 row-panels, bx-major inside a group (8 consecutive
// blocks share a B-column-panel; 2MB A-group stays L2-hot; B repeats hit L3).
template<int DO_GELU>
__global__ __launch_bounds__(256, 4)
void gemm128(const unsigned short* __restrict__ A, const unsigned short* __restrict__ BT,
             const float* __restrict__ bias, unsigned short* __restrict__ C,
             int M, int N, int K)
{
  __shared__ __align__(16) char sA[8192];
  __shared__ __align__(16) char sB[8192];
  const int t = threadIdx.x;
  const int wid = t >> 6, lane = t & 63;
  const int wm = wid >> 1, wn = wid & 1;
  const int lrow = lane & 15, qk = lane >> 4;
  const int dq = qk << 4;

  // block mapping: groups of 8 brow-panels; within a group bx-major
  const int nbx = N >> 7, nby = M >> 7;
  const int per = nbx << 3;
  const int fullg = nby >> 3;
  int by, bx;
  if ((int)blockIdx.x < fullg * per) {
    const int g = blockIdx.x / per, r = blockIdx.x % per;
    by = (g << 3) + (r & 7); bx = r >> 3;
  } else {
    const int r = blockIdx.x - fullg * per;
    const int rem = nby - (fullg << 3);
    by = (fullg << 3) + r % rem; bx = r / rem;
  }
  const int brow = by << 7, bcol = bx << 7;

  // staging constants: 2 glds per matrix per K-step, linear dest t*16
  const int lr1  = t >> 3;                       // LDS row 0..31 (first half)
  const int pp   = (t & 7) << 4;                 // dest byte within 128B row
  const int s1   = pp ^ ((lr1 & 7) << 4);        // inverse-swizzled source pos
  const int row1 = (lr1 << 1) + (s1 >> 6);       // global row (0..63)
  const int col1 = (s1 & 63) >> 1;               // global elem (0..31)
  const size_t aoff1 = (size_t)(brow + row1) * K + col1;
  const size_t aoff2 = (size_t)(brow + row1 + 64) * K + col1;
  const size_t boff1 = (size_t)(bcol + row1) * K + col1;
  const size_t boff2 = (size_t)(bcol + row1 + 64) * K + col1;
  char* dstA1 = sA + t * 16; char* dstA2 = sA + 4096 + t * 16;
  char* dstB1 = sB + t * 16; char* dstB2 = sB + 4096 + t * 16;

  f32x4 acc[4][4] = {};

  for (int k0 = 0; k0 < K; k0 += 32) {
    __syncthreads();                      // prior step's reads complete
    gload_lds16(A  + aoff1 + k0, dstA1);
    gload_lds16(A  + aoff2 + k0, dstA2);
    gload_lds16(BT + boff1 + k0, dstB1);
    gload_lds16(BT + boff2 + k0, dstB2);
    WAITV(0);
    __syncthreads();                      // staged data visible to all waves
    bf16x8 af[4], bf[4];
    #pragma unroll
    for (int mf = 0; mf < 4; ++mf) {
      const int row = wm * 64 + mf * 16 + lrow;
      af[mf] = *(const bf16x8*)(sA + (row >> 1) * 128 +
                ((((row & 1) << 6) | dq) ^ (((row >> 1) & 7) << 4)));
    }
    #pragma unroll
    for (int nf = 0; nf < 4; ++nf) {
      const int row = wn * 64 + nf * 16 + lrow;
      bf[nf] = *(const bf16x8*)(sB + (row >> 1) * 128 +
                ((((row & 1) << 6) | dq) ^ (((row >> 1) & 7) << 4)));
    }
    #pragma unroll
    for (int mf = 0; mf < 4; ++mf)
      #pragma unroll
      for (int nf = 0; nf < 4; ++nf)
        acc[mf][nf] = __builtin_amdgcn_mfma_f32_16x16x32_bf16(af[mf], bf[nf],
                                                              acc[mf][nf], 0, 0, 0);
  }

  // epilogue: bias (+GELU) + bf16 store
  #pragma unroll
  for (int mf = 0; mf < 4; ++mf) {
    #pragma unroll
    for (int nf = 0; nf < 4; ++nf) {
      const int ccol = bcol + wn * 64 + nf * 16 + lrow;
      const float bb = bias[ccol];
      #pragma unroll
      for (int j = 0; j < 4; ++j) {
        const int r = brow + wm * 64 + mf * 16 + qk * 4 + j;
        float v = acc[mf][nf][j] + bb;
        if (DO_GELU) v = 0.5f * v * (1.0f + erff(v * 0.70710678118654752f));
        C[(size_t)r * N + ccol] = f2bf(v);
      }
    }
  }
}

// ---------------- FEM: 3 blockwise instance-norm gates fused + residual ----------------
__device__ __forceinline__ void fem_block(unsigned short* col, int t,
                                          int h0, int nh, int w0, int nw)
{
  float s = 0.f, s2 = 0.f;
  for (int ih = 0; ih < nh; ih++)
    for (int iw = 0; iw < nw; iw++) {
      const float v = bf2f(col[((h0 + ih) * 14 + w0 + iw) * 128 + t]);
      s += v; s2 += v * v;
    }
  const float inv = 1.0f / (float)(nh * nw);
  const float m = s * inv;
  const float var = s2 * inv - m * m;
  const float r = rsqrtf(var + 1e-5f);
  for (int ih = 0; ih < nh; ih++)
    for (int iw = 0; iw < nw; iw++) {
      const int idx = ((h0 + ih) * 14 + w0 + iw) * 128 + t;
      const float v = bf2f(col[idx]);
      const float a = 1.0f / (1.0f + __expf(-(v - m) * r));
      col[idx] = f2bf(0.5f * v * (1.0f + a));
    }
}

__global__ __launch_bounds__(128)
void fem_kernel(const unsigned short* __restrict__ z, const float* __restrict__ x,
                float* __restrict__ out)
{
  __shared__ unsigned short buf[CN * 128];   // 50,176 B; thread-private columns
  const int t = threadIdx.x;
  const int b = blockIdx.x >> 3;
  const int cc = blockIdx.x & 7;
  const int c = cc * 128 + t;
  const size_t base = (size_t)b * CN * CC + c;
  #pragma unroll 4
  for (int n = 0; n < CN; n++) buf[n * 128 + t] = z[base + (size_t)n * CC];
  // s = 3: 5x5 blocks, row/col starts {0,3,6,9,12}, lens {3,3,3,3,2}
  const int st3[5] = {0, 3, 6, 9, 12};
  const int ln3[5] = {3, 3, 3, 3, 2};
  for (int i = 0; i < 5; i++)
    for (int j = 0; j < 5; j++)
      fem_block(buf, t, st3[i], ln3[i], st3[j], ln3[j]);
  // s = 7: 2x2 blocks of 7x7
  for (int i = 0; i < 2; i++)
    for (int j = 0; j < 2; j++)
      fem_block(buf, t, i * 7, 7, j * 7, 7);
  // s = 14: whole field
  fem_block(buf, t, 0, 14, 0, 14);
  #pragma unroll 4
  for (int n = 0; n < CN; n++)
    out[base + (size_t)n * CC] = x[base + (size_t)n * CC] + bf2f(buf[n * 128 + t]);
}

// ---------------- launch ----------------
extern "C" void kernel_launch(void* const* d_in, const int* in_sizes, int n_in,
                              void* d_out, int out_size, void* d_ws, size_t ws_size,
                              hipStream_t stream) {
  const float* x     = (const float*)d_in[0];
  const float* ln1_g = (const float*)d_in[1];
  const float* ln1_b = (const float*)d_in[2];
  const float* cw    = (const float*)d_in[3];
  const float* ln2_g = (const float*)d_in[4];
  const float* ln2_b = (const float*)d_in[5];
  const float* fc1_w = (const float*)d_in[6];
  const float* fc1_b = (const float*)d_in[7];
  const float* fc2_w = (const float*)d_in[8];
  const float* fc2_b = (const float*)d_in[9];
  float* out = (float*)d_out;
  char* ws = (char*)d_ws;

  // arena (total 161.5 MB); d_out doubles as fp32 scratch for y1/y2
  const size_t SZ_A = (size_t)CB * CHH * CKW * CC * 4;       // 29,360,128 B
  float* Ar = (float*)(ws);
  float* Ai = (float*)(ws + SZ_A);
  float* Br = (float*)(ws + 2 * SZ_A);
  float* Bi = (float*)(ws + 3 * SZ_A);
  unsigned short* A1   = (unsigned short*)(ws);                        // after FFT done
  unsigned short* W1T  = (unsigned short*)(ws + SZ_A);                 // [4096,1024] bf16
  unsigned short* W2T  = (unsigned short*)(ws + SZ_A + (size_t)4096 * 1024 * 2); // [1024,4096]
  unsigned short* Hmid = (unsigned short*)(ws + 2 * SZ_A);             // [12544,4096] bf16
  unsigned short* Z    = (unsigned short*)(ws);                        // [12544,1024] bf16

  // 1. LN1: x -> y1 (in d_out)
  ln_kernel<0><<<CROWS, 256, 0, stream>>>(x, ln1_g, ln1_b, out, nullptr);
  // 2. rfft along W
  fft_w_fwd<<<CB * CHH * 4, 256, 0, stream>>>(out, Ar, Ai);
  // 3. fft along H + filter + ifft along H
  fft_h_filt<<<CB * CKW * 4, 256, 0, stream>>>(Ar, Ai, cw, Br, Bi);
  // 4. irfft along W -> y2 (in d_out)
  fft_w_inv<<<CB * CHH * 4, 256, 0, stream>>>(Br, Bi, out);
  // 5. LN2 -> bf16 A1
  ln_kernel<1><<<CROWS, 256, 0, stream>>>(out, ln2_g, ln2_b, nullptr, A1);
  // 6. weight prep (FFT intermediates dead)
  transpose_f32_bf16<<<dim3(4096 / 32, 1024 / 32), 256, 0, stream>>>(fc1_w, W1T, 1024, 4096);
  transpose_f32_bf16<<<dim3(1024 / 32, 4096 / 32), 256, 0, stream>>>(fc2_w, W2T, 4096, 1024);
  // 7. GEMM1 + bias + exact GELU -> Hmid bf16 (grid 32x98 = 3136)
  gemm128<1><<<dim3(3136), 256, 0, stream>>>(A1, W1T, fc1_b, Hmid, CROWS, 4096, 1024);
  // 8. GEMM2 + bias -> Z bf16 (grid 8x98 = 784)
  gemm128<0><<<dim3(784), 256, 0, stream>>>(Hmid, W2T, fc2_b, Z, CROWS, 1024, 4096);
  // 9. FEM x3 fused + residual -> out
  fem_kernel<<<CB * 8, 128, 0, stream>>>(Z, x, out);
}